// Round 12
// baseline (256.693 us; speedup 1.0000x reference)
//
#include <hip/hip_runtime.h>

// Conv2d 7x7 s2 p3, 1ch, 8192^2 fp32 -> 4096^2 fp32.
// Round 12: NO-LDS streaming. 256x16 output tile / 256 threads, 4x4 per
// thread (64 tx, 4 ty). Each thread reads its 13 input rows x 4 aligned
// float4 directly from global (L1/L2 serve within-wave overlap + 5-row
// vertical halo), scatter-accumulates into 16 regs. No barrier, no LDS.
// XCD swizzle: xcd=bid&7 owns 2 tile-columns, by fastest (r11's win).
// Nontemporal stores. Edges (3% of blocks): per-chunk bounds-checked path.

#define THREADS 256
#define TILE_W 256
#define TILE_H 16
#define IMG 8192
#define OUTW 4096
#define GRIDX 16
#define GRIDY 256

typedef float __attribute__((ext_vector_type(4))) floatx4;

__global__ __launch_bounds__(THREADS, 4)
void conv7x7_s2(const float* __restrict__ x, const float* __restrict__ wgt,
                const float* __restrict__ bias, float* __restrict__ out) {
  const int t = threadIdx.x;

  // ---- XCD-aware swizzle (r11): 4096 blocks, 512/XCD = 2 cols x 256 rows ----
  const int bid = blockIdx.x + GRIDX * blockIdx.y;
  const int xcd = bid & 7;
  const int local = bid >> 3;             // 0..511
  const int bx = 2 * xcd + (local >> 8);  // 2 tile-columns per XCD
  const int by = local & 255;             // by fastest

  const int tile_x = bx * TILE_W;
  const int tile_y = by * TILE_H;

  float wv[49];
#pragma unroll
  for (int i = 0; i < 49; ++i) wv[i] = wgt[i];   // uniform -> SGPRs
  const float bv = bias[0];

  const int tx = t & 63;          // 0..63 -> 256 out cols (4 each)
  const int ty = t >> 6;          // 0..3  -> 4 out rows each
  const int gr0 = tile_y * 2 + 8 * ty - 3;   // first input row of window
  const int gc0 = tile_x * 2 + 8 * tx - 4;   // aligned first input col

  float acc[4][4];
#pragma unroll
  for (int y = 0; y < 4; ++y)
#pragma unroll
    for (int xx = 0; xx < 4; ++xx) acc[y][xx] = bv;

  const bool interior = (bx >= 1) & (bx <= 14) & (by >= 1) & (by <= 254);

  // rbuf[i] = input col (gc0+i); out col 4tx+xx needs rbuf[2xx+kw+1]
#define FMA_ROW(J)                                                          \
  {                                                                         \
    _Pragma("unroll") for (int y = 0; y < 4; ++y) {                         \
      const int kh = (J) - 2 * y;                                           \
      if (kh >= 0 && kh <= 6) {                                             \
        _Pragma("unroll") for (int xx = 0; xx < 4; ++xx)                    \
            _Pragma("unroll") for (int kw = 0; kw < 7; ++kw)                \
                acc[y][xx] =                                                \
                    fmaf(rbuf[2 * xx + kw + 1], wv[kh * 7 + kw], acc[y][xx]); \
      }                                                                     \
    }                                                                       \
  }

  if (interior) {
#pragma unroll
    for (int j = 0; j < 13; ++j) {
      const float* rp = x + (long long)(gr0 + j) * IMG + gc0;
      float rbuf[16];
      const float4 v0 = *reinterpret_cast<const float4*>(rp);
      const float4 v1 = *reinterpret_cast<const float4*>(rp + 4);
      const float4 v2 = *reinterpret_cast<const float4*>(rp + 8);
      const float4 v3 = *reinterpret_cast<const float4*>(rp + 12);
      rbuf[0] = v0.x;  rbuf[1] = v0.y;  rbuf[2] = v0.z;  rbuf[3] = v0.w;
      rbuf[4] = v1.x;  rbuf[5] = v1.y;  rbuf[6] = v1.z;  rbuf[7] = v1.w;
      rbuf[8] = v2.x;  rbuf[9] = v2.y;  rbuf[10] = v2.z; rbuf[11] = v2.w;
      rbuf[12] = v3.x; rbuf[13] = v3.y; rbuf[14] = v3.z; rbuf[15] = v3.w;
      FMA_ROW(j);
    }
  } else {
#pragma unroll
    for (int j = 0; j < 13; ++j) {
      const int gr = gr0 + j;
      const bool rok = (unsigned)gr < (unsigned)IMG;
      const float* rp = x + (long long)gr * IMG;
      float rbuf[16];
#pragma unroll
      for (int k = 0; k < 4; ++k) {
        const int gc = gc0 + 4 * k;
        float4 v = make_float4(0.f, 0.f, 0.f, 0.f);
        if (rok && (unsigned)gc < (unsigned)(IMG - 3))
          v = *reinterpret_cast<const float4*>(rp + gc);
        rbuf[4 * k + 0] = v.x;
        rbuf[4 * k + 1] = v.y;
        rbuf[4 * k + 2] = v.z;
        rbuf[4 * k + 3] = v.w;
      }
      FMA_ROW(j);
    }
  }

  // ---- store: 4 x nontemporal dwordx4, 1KB contiguous per wave-row ----
  const int ox = tile_x + 4 * tx;
  const int oy0 = tile_y + 4 * ty;
#pragma unroll
  for (int y = 0; y < 4; ++y) {
    floatx4 v;
    v.x = acc[y][0]; v.y = acc[y][1]; v.z = acc[y][2]; v.w = acc[y][3];
    __builtin_nontemporal_store(
        v, reinterpret_cast<floatx4*>(&out[(long long)(oy0 + y) * OUTW + ox]));
  }
}

extern "C" void kernel_launch(void* const* d_in, const int* in_sizes, int n_in,
                              void* d_out, int out_size, void* d_ws, size_t ws_size,
                              hipStream_t stream) {
  const float* x = (const float*)d_in[0];
  const float* w = (const float*)d_in[1];
  const float* b = (const float*)d_in[2];
  float* out = (float*)d_out;
  dim3 grid(GRIDX, GRIDY);  // 16 x 256 = 4096 blocks
  conv7x7_s2<<<grid, dim3(THREADS), 0, stream>>>(x, w, b, out);
}

// Round 13
// 126.588 us; speedup vs baseline: 2.0278x; 2.0278x over previous
//
#include <hip/hip_runtime.h>

// Conv2d 7x7 s2 p3, 1ch, 8192^2 fp32 -> 4096^2 fp32.
// r11 geometry (best 59.3us: 256x8 tiles, 2080B segments, parity LDS,
// XCD swizzle, nontemporal stores) + 2-tile in-block pipeline (T14):
// each block computes two vertically adjacent 256x8 tiles; tile-B global
// loads are issued BEFORE tile-A compute, ds_write(B) happens after the
// WAR barrier -> HBM latency hidden under compute. 3 barriers / 2 tiles.

#define THREADS 256
#define TILE_W 256
#define IN_H 21              // 8*2 + 5
#define CHUNKS 130           // float4 chunks per input row (520 cols)
#define ROWF (CHUNKS * 4)
#define NSLOT (IN_H * CHUNKS)       // 2730
#define NROUND 11                   // ceil(2730/256)
#define NSLOT_PAD (NROUND * THREADS)  // 2816 -> 45056 B LDS (3 blocks/CU)
#define IMG 8192
#define OUTW 4096
#define GRIDX 16
#define GRIDY 256                   // each block: 16 output rows (2 sub-tiles)

typedef float __attribute__((ext_vector_type(4))) floatx4;

__global__ __launch_bounds__(THREADS, 3)
void conv7x7_s2(const float* __restrict__ x, const float* __restrict__ wgt,
                const float* __restrict__ bias, float* __restrict__ out) {
  __shared__ __align__(16) float lds[NSLOT_PAD * 4];
  const int t = threadIdx.x;

  // ---- XCD swizzle: 4096 blocks, 512/XCD = 2 tile-cols x 256 row-pairs ----
  const int bid = blockIdx.x + GRIDX * blockIdx.y;
  const int xcd = bid & 7;
  const int local = bid >> 3;             // 0..511
  const int bx = 2 * xcd + (local >> 8);
  const int byp = local & 255;            // row-pair index, fastest

  const int tile_x = bx * TILE_W;
  const int tile_y0 = byp * 16;           // 16 output rows per block
  const int g0c4 = tile_x * 2 - 4;        // aligned input col of chunk 0
  const int g0rA = tile_y0 * 2 - 3;       // input row 0 of sub-tile A

  float wv[49];
#pragma unroll
  for (int i = 0; i < 49; ++i) wv[i] = wgt[i];   // uniform -> SGPRs
  const float bv = bias[0];

  const bool interior = (bx >= 1) & (bx <= 14) & (byp >= 1) & (byp <= 254);

  // staging decomposition (shared by both tiles)
  int s_r[NROUND], s_g[NROUND];
#pragma unroll
  for (int i = 0; i < NROUND; ++i) {
    const int s = t + THREADS * i;
    s_r[i] = s / CHUNKS;             // magic-mul div
    s_g[i] = s - s_r[i] * CHUNKS;    // global chunk within row
  }

  float4 vbuf[NROUND];

  auto LOAD = [&](int g0r) {
    if (interior) {
      const float* xb = x + (long long)g0r * IMG + g0c4;
#pragma unroll
      for (int i = 0; i < NROUND; ++i) {
        if (t + THREADS * i < NSLOT)
          vbuf[i] = *reinterpret_cast<const float4*>(
              xb + (long long)s_r[i] * IMG + 4 * s_g[i]);
      }
    } else {
#pragma unroll
      for (int i = 0; i < NROUND; ++i) {
        const int s = t + THREADS * i;
        const int gr = g0r + s_r[i];
        const int gc = g0c4 + 4 * s_g[i];
        float4 v = make_float4(0.f, 0.f, 0.f, 0.f);
        if (s < NSLOT && (unsigned)gr < (unsigned)IMG &&
            (unsigned)gc < (unsigned)(IMG - 3))
          v = *reinterpret_cast<const float4*>(&x[(long long)gr * IMG + gc]);
        vbuf[i] = v;
      }
    }
  };

  auto WRITE = [&]() {
#pragma unroll
    for (int i = 0; i < NROUND; ++i) {
      const int s = t + THREADS * i;
      if (s < NSLOT) {
        const int g = s_g[i];
        const int sl = (g & 1) ? (65 + (g >> 1)) : (g >> 1);  // parity slot
        *reinterpret_cast<float4*>(&lds[(s_r[i] * CHUNKS + sl) * 4]) = vbuf[i];
      }
    }
  };

  const int tx = t & 63;          // 0..63 -> 256 output cols
  const int ty = t >> 6;          // 0..3  -> 2 output rows each

  auto COMPUTE_STORE = [&](int sub) {
    float acc[2][4];
#pragma unroll
    for (int y = 0; y < 2; ++y)
#pragma unroll
      for (int xx = 0; xx < 4; ++xx) acc[y][xx] = bv;

#pragma unroll
    for (int j = 0; j < 9; ++j) {
      const int sl = 4 * ty + j;    // LDS input row, max 20
      const float* rp = &lds[sl * ROWF];
      float rbuf[16];
      const float4 v0 = *reinterpret_cast<const float4*>(rp + (tx) * 4);
      const float4 v1 = *reinterpret_cast<const float4*>(rp + (65 + tx) * 4);
      const float4 v2 = *reinterpret_cast<const float4*>(rp + (tx + 1) * 4);
      const float4 v3 = *reinterpret_cast<const float4*>(rp + (66 + tx) * 4);
      rbuf[0] = v0.x;  rbuf[1] = v0.y;  rbuf[2] = v0.z;  rbuf[3] = v0.w;
      rbuf[4] = v1.x;  rbuf[5] = v1.y;  rbuf[6] = v1.z;  rbuf[7] = v1.w;
      rbuf[8] = v2.x;  rbuf[9] = v2.y;  rbuf[10] = v2.z; rbuf[11] = v2.w;
      rbuf[12] = v3.x; rbuf[13] = v3.y; rbuf[14] = v3.z; rbuf[15] = v3.w;
      // rbuf[i] = input col (8tx+i) rel. g0c4; out col 4tx+xx needs 8tx+2xx+kw+1
#pragma unroll
      for (int y = 0; y < 2; ++y) {
        const int kh = j - 2 * y;
        if (kh >= 0 && kh <= 6) {
#pragma unroll
          for (int xx = 0; xx < 4; ++xx)
#pragma unroll
            for (int kw = 0; kw < 7; ++kw)
              acc[y][xx] = fmaf(rbuf[2 * xx + kw + 1], wv[kh * 7 + kw], acc[y][xx]);
        }
      }
    }
    const int ox = tile_x + 4 * tx;
    const int oy = tile_y0 + 8 * sub + 2 * ty;
#pragma unroll
    for (int y = 0; y < 2; ++y) {
      floatx4 v;
      v.x = acc[y][0]; v.y = acc[y][1]; v.z = acc[y][2]; v.w = acc[y][3];
      __builtin_nontemporal_store(
          v, reinterpret_cast<floatx4*>(&out[(long long)(oy + y) * OUTW + ox]));
    }
  };

  // ---- pipeline: stage A | issue B | compute A | WAR-barrier | write B ----
  LOAD(g0rA);
  WRITE();
  __syncthreads();

  LOAD(g0rA + 16);      // tile-B loads in flight during compute(A)
  COMPUTE_STORE(0);
  __syncthreads();      // WAR: all waves done reading tile A
  WRITE();              // vmcnt drains here, latency hidden under compute(A)
  __syncthreads();
  COMPUTE_STORE(1);
}

extern "C" void kernel_launch(void* const* d_in, const int* in_sizes, int n_in,
                              void* d_out, int out_size, void* d_ws, size_t ws_size,
                              hipStream_t stream) {
  const float* x = (const float*)d_in[0];
  const float* w = (const float*)d_in[1];
  const float* b = (const float*)d_in[2];
  float* out = (float*)d_out;
  dim3 grid(GRIDX, GRIDY);  // 16 x 256 = 4096 blocks
  conv7x7_s2<<<grid, dim3(THREADS), 0, stream>>>(x, w, b, out);
}

// Round 14
// 73.031 us; speedup vs baseline: 3.5149x; 1.7334x over previous
//
#include <hip/hip_runtime.h>

// Conv2d 7x7 s2 p3, 1ch, 8192^2 fp32 -> 4096^2 fp32.
// r11 config (59.3us) with ONE change: plain float4 stores instead of
// __builtin_nontemporal_store. r12/r13 counters revealed nt stores cause
// ~2.9x WRITE amplification (185-214MB for a 64MB output) on gfx950 --
// nt bypasses L2 write-coalescing; 16B stores reach the MC uncombined.
// 256x8 output tile / 256-thread block, 4x2 outputs per thread.
// XCD swizzle: xcd=bid&7 owns 2 tile-columns, by fastest (L2-resident strip).
// LDS: 21 rows x 130 chunks, parity-interleaved slots; conflict-free reads.
// Register staging, dense global reads (2080B contiguous per row segment).

#define THREADS 256
#define TILE_W 256
#define TILE_H 8
#define IN_H 21              // TILE_H*2 + 5
#define CHUNKS 130           // float4 chunks per input row (520 cols)
#define ROWF (CHUNKS * 4)    // floats per LDS row
#define NSLOT (IN_H * CHUNKS)   // 2730
#define NROUND 11               // ceil(2730/256)
#define NSLOT_PAD (NROUND * THREADS)  // 2816 chunks -> 45056 B LDS
#define IMG 8192
#define OUTW 4096
#define GRIDX 16

__global__ __launch_bounds__(THREADS, 3)
void conv7x7_s2(const float* __restrict__ x, const float* __restrict__ wgt,
                const float* __restrict__ bias, float* __restrict__ out) {
  __shared__ __align__(16) float lds[NSLOT_PAD * 4];
  const int t = threadIdx.x;

  // ---- XCD-aware swizzle: bid -> (bx, by), by fastest within an XCD ----
  const int bid = blockIdx.x + GRIDX * blockIdx.y;  // dispatch-linear
  const int xcd = bid & 7;
  const int local = bid >> 3;            // 0..1023 per XCD
  const int bx = 2 * xcd + (local >> 9); // 2 tile-columns per XCD
  const int by = local & 511;

  const int tile_x = bx * TILE_W;
  const int tile_y = by * TILE_H;
  const int g0c4 = tile_x * 2 - 4;  // aligned input col of chunk 0
  const int g0r = tile_y * 2 - 3;   // input row of LDS row 0

  float wv[49];
#pragma unroll
  for (int i = 0; i < 49; ++i) wv[i] = wgt[i];   // uniform -> SGPRs
  const float bv = bias[0];

  const bool interior = (bx >= 1) & (bx <= 14) & (by >= 1) & (by <= 510);

  // ---- staging: dense global loads -> regs, parity-scattered ds_writes ----
  float4 vbuf[NROUND];
  if (interior) {
    const float* xb = x + (long long)g0r * IMG + g0c4;
#pragma unroll
    for (int i = 0; i < NROUND; ++i) {
      const int s = t + THREADS * i;      // dense: lane-consecutive chunks
      if (s < NSLOT) {
        const int r = s / CHUNKS;          // magic-mul div
        const int g = s - r * CHUNKS;      // global chunk within row
        vbuf[i] = *reinterpret_cast<const float4*>(xb + (long long)r * IMG + 4 * g);
      }
    }
  } else {
#pragma unroll
    for (int i = 0; i < NROUND; ++i) {
      const int s = t + THREADS * i;
      const int r = s / CHUNKS;
      const int g = s - r * CHUNKS;
      const int gr = g0r + r;
      const int gc = g0c4 + 4 * g;
      float4 v = make_float4(0.f, 0.f, 0.f, 0.f);
      if (s < NSLOT && (unsigned)gr < (unsigned)IMG &&
          (unsigned)gc < (unsigned)(IMG - 3))
        v = *reinterpret_cast<const float4*>(&x[(long long)gr * IMG + gc]);
      vbuf[i] = v;
    }
  }
#pragma unroll
  for (int i = 0; i < NROUND; ++i) {
    const int s = t + THREADS * i;
    if (s < NSLOT) {
      const int r = s / CHUNKS;
      const int g = s - r * CHUNKS;
      const int sl = (g & 1) ? (65 + (g >> 1)) : (g >> 1);  // parity slot
      *reinterpret_cast<float4*>(&lds[(r * CHUNKS + sl) * 4]) = vbuf[i];
    }
  }
  __syncthreads();

  // ---- compute: 4 wide x 2 tall per thread ----
  const int tx = t & 63;          // 0..63 -> 256 output cols
  const int ty = t >> 6;          // 0..3  -> 2 output rows each
  float acc[2][4];
#pragma unroll
  for (int y = 0; y < 2; ++y)
#pragma unroll
    for (int xx = 0; xx < 4; ++xx) acc[y][xx] = bv;

#pragma unroll
  for (int j = 0; j < 9; ++j) {
    const int sl = 4 * ty + j;    // LDS input row, max 20
    const float* rp = &lds[sl * ROWF];
    float rbuf[16];
    // chunks 2tx..2tx+3 -> slots tx, 65+tx, tx+1, 66+tx (dense across wave)
    {
      const float4 v0 = *reinterpret_cast<const float4*>(rp + (tx) * 4);
      const float4 v1 = *reinterpret_cast<const float4*>(rp + (65 + tx) * 4);
      const float4 v2 = *reinterpret_cast<const float4*>(rp + (tx + 1) * 4);
      const float4 v3 = *reinterpret_cast<const float4*>(rp + (66 + tx) * 4);
      rbuf[0] = v0.x;  rbuf[1] = v0.y;  rbuf[2] = v0.z;  rbuf[3] = v0.w;
      rbuf[4] = v1.x;  rbuf[5] = v1.y;  rbuf[6] = v1.z;  rbuf[7] = v1.w;
      rbuf[8] = v2.x;  rbuf[9] = v2.y;  rbuf[10] = v2.z; rbuf[11] = v2.w;
      rbuf[12] = v3.x; rbuf[13] = v3.y; rbuf[14] = v3.z; rbuf[15] = v3.w;
    }
    // rbuf[i] = input col (8tx+i) rel. to g0c4; out col 4tx+xx needs 8tx+2xx+kw+1
#pragma unroll
    for (int y = 0; y < 2; ++y) {
      const int kh = j - 2 * y;
      if (kh >= 0 && kh <= 6) {
#pragma unroll
        for (int xx = 0; xx < 4; ++xx)
#pragma unroll
          for (int kw = 0; kw < 7; ++kw)
            acc[y][xx] = fmaf(rbuf[2 * xx + kw + 1], wv[kh * 7 + kw], acc[y][xx]);
      }
    }
  }

  // ---- store: plain dwordx4, 1KB contiguous per wave-row ----
  const int ox = tile_x + 4 * tx;
  const int oy = tile_y + 2 * ty;
#pragma unroll
  for (int y = 0; y < 2; ++y) {
    float4 v = make_float4(acc[y][0], acc[y][1], acc[y][2], acc[y][3]);
    *reinterpret_cast<float4*>(&out[(long long)(oy + y) * OUTW + ox]) = v;
  }
}

extern "C" void kernel_launch(void* const* d_in, const int* in_sizes, int n_in,
                              void* d_out, int out_size, void* d_ws, size_t ws_size,
                              hipStream_t stream) {
  const float* x = (const float*)d_in[0];
  const float* w = (const float*)d_in[1];
  const float* b = (const float*)d_in[2];
  float* out = (float*)d_out;
  dim3 grid(GRIDX, OUTW / TILE_H);  // 16 x 512
  conv7x7_s2<<<grid, dim3(THREADS), 0, stream>>>(x, w, b, out);
}

// Round 17
// 59.536 us; speedup vs baseline: 4.3116x; 1.2267x over previous
//
#include <hip/hip_runtime.h>

// Conv2d 7x7 s2 p3, 1ch, 8192^2 fp32 -> 4096^2 fp32.  FINAL (r11 config).
// 256x8 output tile / 256-thread block, 4x2 outputs per thread.
// - Dense register staging: 2080B contiguous row segments (DRAM page locality).
// - Parity-interleaved LDS slots (even->0..64, odd->65..129): conflict-free
//   ds_read_b128 (64 consecutive slots across the wave).
// - XCD-aware swizzle: xcd=bid&7 owns 2 tile-columns, by fastest -> each
//   XCD's concurrent input strip (~3.2MB) is L2-resident.
// - __builtin_nontemporal_store (nt sc0 sc1): no write-allocate, input stays
//   L2-resident. (Coherent-nt write amplification ~2.9x is measured (r13) but
//   unavoidable: plain stores thrash L2 (r14 +14us), bare-nt is incoherent
//   (r15/r16 fail).)
// Effective memory traffic 204MB fetch + ~185MB write = 389MB / 59.3us
// = 6.6 TB/s ~= chip memory ceiling.

#define THREADS 256
#define TILE_W 256
#define TILE_H 8
#define IN_H 21              // TILE_H*2 + 5
#define CHUNKS 130           // float4 chunks per input row (520 cols)
#define ROWF (CHUNKS * 4)    // floats per LDS row
#define NSLOT (IN_H * CHUNKS)   // 2730
#define NROUND 11               // ceil(2730/256)
#define NSLOT_PAD (NROUND * THREADS)  // 2816 chunks -> 45056 B LDS
#define IMG 8192
#define OUTW 4096
#define GRIDX 16

typedef float __attribute__((ext_vector_type(4))) floatx4;

__global__ __launch_bounds__(THREADS, 3)
void conv7x7_s2(const float* __restrict__ x, const float* __restrict__ wgt,
                const float* __restrict__ bias, float* __restrict__ out) {
  __shared__ __align__(16) float lds[NSLOT_PAD * 4];
  const int t = threadIdx.x;

  // ---- XCD-aware swizzle: bid -> (bx, by), by fastest within an XCD ----
  const int bid = blockIdx.x + GRIDX * blockIdx.y;  // dispatch-linear
  const int xcd = bid & 7;
  const int local = bid >> 3;            // 0..1023 per XCD
  const int bx = 2 * xcd + (local >> 9); // 2 tile-columns per XCD
  const int by = local & 511;

  const int tile_x = bx * TILE_W;
  const int tile_y = by * TILE_H;
  const int g0c4 = tile_x * 2 - 4;  // aligned input col of chunk 0
  const int g0r = tile_y * 2 - 3;   // input row of LDS row 0

  float wv[49];
#pragma unroll
  for (int i = 0; i < 49; ++i) wv[i] = wgt[i];   // uniform -> SGPRs
  const float bv = bias[0];

  const bool interior = (bx >= 1) & (bx <= 14) & (by >= 1) & (by <= 510);

  // ---- staging: dense global loads -> regs, parity-scattered ds_writes ----
  float4 vbuf[NROUND];
  if (interior) {
    const float* xb = x + (long long)g0r * IMG + g0c4;
#pragma unroll
    for (int i = 0; i < NROUND; ++i) {
      const int s = t + THREADS * i;      // dense: lane-consecutive chunks
      if (s < NSLOT) {
        const int r = s / CHUNKS;          // magic-mul div
        const int g = s - r * CHUNKS;      // global chunk within row
        vbuf[i] = *reinterpret_cast<const float4*>(xb + (long long)r * IMG + 4 * g);
      }
    }
  } else {
#pragma unroll
    for (int i = 0; i < NROUND; ++i) {
      const int s = t + THREADS * i;
      const int r = s / CHUNKS;
      const int g = s - r * CHUNKS;
      const int gr = g0r + r;
      const int gc = g0c4 + 4 * g;
      float4 v = make_float4(0.f, 0.f, 0.f, 0.f);
      if (s < NSLOT && (unsigned)gr < (unsigned)IMG &&
          (unsigned)gc < (unsigned)(IMG - 3))
        v = *reinterpret_cast<const float4*>(&x[(long long)gr * IMG + gc]);
      vbuf[i] = v;
    }
  }
#pragma unroll
  for (int i = 0; i < NROUND; ++i) {
    const int s = t + THREADS * i;
    if (s < NSLOT) {
      const int r = s / CHUNKS;
      const int g = s - r * CHUNKS;
      const int sl = (g & 1) ? (65 + (g >> 1)) : (g >> 1);  // parity slot
      *reinterpret_cast<float4*>(&lds[(r * CHUNKS + sl) * 4]) = vbuf[i];
    }
  }
  __syncthreads();

  // ---- compute: 4 wide x 2 tall per thread ----
  const int tx = t & 63;          // 0..63 -> 256 output cols
  const int ty = t >> 6;          // 0..3  -> 2 output rows each
  float acc[2][4];
#pragma unroll
  for (int y = 0; y < 2; ++y)
#pragma unroll
    for (int xx = 0; xx < 4; ++xx) acc[y][xx] = bv;

#pragma unroll
  for (int j = 0; j < 9; ++j) {
    const int sl = 4 * ty + j;    // LDS input row, max 20
    const float* rp = &lds[sl * ROWF];
    float rbuf[16];
    // chunks 2tx..2tx+3 -> slots tx, 65+tx, tx+1, 66+tx (dense across wave)
    {
      const float4 v0 = *reinterpret_cast<const float4*>(rp + (tx) * 4);
      const float4 v1 = *reinterpret_cast<const float4*>(rp + (65 + tx) * 4);
      const float4 v2 = *reinterpret_cast<const float4*>(rp + (tx + 1) * 4);
      const float4 v3 = *reinterpret_cast<const float4*>(rp + (66 + tx) * 4);
      rbuf[0] = v0.x;  rbuf[1] = v0.y;  rbuf[2] = v0.z;  rbuf[3] = v0.w;
      rbuf[4] = v1.x;  rbuf[5] = v1.y;  rbuf[6] = v1.z;  rbuf[7] = v1.w;
      rbuf[8] = v2.x;  rbuf[9] = v2.y;  rbuf[10] = v2.z; rbuf[11] = v2.w;
      rbuf[12] = v3.x; rbuf[13] = v3.y; rbuf[14] = v3.z; rbuf[15] = v3.w;
    }
    // rbuf[i] = input col (8tx+i) rel. to g0c4; out col 4tx+xx needs 8tx+2xx+kw+1
#pragma unroll
    for (int y = 0; y < 2; ++y) {
      const int kh = j - 2 * y;
      if (kh >= 0 && kh <= 6) {
#pragma unroll
        for (int xx = 0; xx < 4; ++xx)
#pragma unroll
          for (int kw = 0; kw < 7; ++kw)
            acc[y][xx] = fmaf(rbuf[2 * xx + kw + 1], wv[kh * 7 + kw], acc[y][xx]);
      }
    }
  }

  // ---- store: nontemporal (coherent nt sc0 sc1), 1KB contiguous/wave-row ----
  const int ox = tile_x + 4 * tx;
  const int oy = tile_y + 2 * ty;
#pragma unroll
  for (int y = 0; y < 2; ++y) {
    floatx4 v;
    v.x = acc[y][0]; v.y = acc[y][1]; v.z = acc[y][2]; v.w = acc[y][3];
    __builtin_nontemporal_store(
        v, reinterpret_cast<floatx4*>(&out[(long long)(oy + y) * OUTW + ox]));
  }
}

extern "C" void kernel_launch(void* const* d_in, const int* in_sizes, int n_in,
                              void* d_out, int out_size, void* d_ws, size_t ws_size,
                              hipStream_t stream) {
  const float* x = (const float*)d_in[0];
  const float* w = (const float*)d_in[1];
  const float* b = (const float*)d_in[2];
  float* out = (float*)d_out;
  dim3 grid(GRIDX, OUTW / TILE_H);  // 16 x 512
  conv7x7_s2<<<grid, dim3(THREADS), 0, stream>>>(x, w, b, out);
}